// Round 1
// baseline (761.423 us; speedup 1.0000x reference)
//
#include <hip/hip_runtime.h>

#define D 512

typedef __bf16 bf16x8 __attribute__((ext_vector_type(8)));
typedef float f32x4 __attribute__((ext_vector_type(4)));

__device__ __forceinline__ unsigned short f2bf(float f){
  union { float f; unsigned u; } v; v.f = f;
  unsigned r = v.u + 0x7fffu + ((v.u >> 16) & 1u);
  return (unsigned short)(r >> 16);
}
__device__ __forceinline__ float bf2f(unsigned h){
  union { unsigned u; float f; } v; v.u = h << 16; return v.f;
}

// ---------------- f32 -> bf16 convert ----------------
__global__ void k_f2b(const float* __restrict__ in, unsigned short* __restrict__ out, int n){
  int i = blockIdx.x*blockDim.x + threadIdx.x;
  if (i < n) out[i] = f2bf(in[i]);
}

// ---------------- gather rows (optionally a[idx]-b[idx]) -> bf16 ----------------
__global__ __launch_bounds__(256) void k_gather_sub_bf16(
    const float* __restrict__ a, const float* __restrict__ b,
    const int* __restrict__ idx, unsigned short* __restrict__ out, int nrows)
{
  int g = blockIdx.x*256 + threadIdx.x;
  int total = nrows << 7;            // nrows * 128 threads (4 cols each)
  if (g >= total) return;
  int row = g >> 7, q = (g & 127) << 2;
  int s = idx[row];
  float4 va = *(const float4*)(a + (size_t)s*D + q);
  float4 o;
  if (b){
    float4 vb = *(const float4*)(b + (size_t)s*D + q);
    o.x = va.x - vb.x; o.y = va.y - vb.y; o.z = va.z - vb.z; o.w = va.w - vb.w;
  } else {
    o = va;
  }
  ushort4 r;
  r.x = f2bf(o.x); r.y = f2bf(o.y); r.z = f2bf(o.z); r.w = f2bf(o.w);
  *(ushort4*)(out + (size_t)row*D + q) = r;
}

// ---------------- CSR build ----------------
__global__ void k_count(const int* __restrict__ rows, int* __restrict__ cnt, int E){
  int e = blockIdx.x*blockDim.x + threadIdx.x;
  if (e < E) atomicAdd(&cnt[rows[e]], 1);
}

__global__ __launch_bounds__(1024) void k_exscan4(
    const int* c0, int* r0, int n0,
    const int* c1, int* r1, int n1,
    const int* c2, int* r2, int n2,
    const int* c3, int* r3, int n3)
{
  __shared__ int part[1024];
  const int* cnt; int* rp; int n;
  switch (blockIdx.x){
    case 0: cnt=c0; rp=r0; n=n0; break;
    case 1: cnt=c1; rp=r1; n=n1; break;
    case 2: cnt=c2; rp=r2; n=n2; break;
    default: cnt=c3; rp=r3; n=n3; break;
  }
  int t = threadIdx.x;
  int chunk = n >> 10;               // n divisible by 1024
  int base = t*chunk;
  int s = 0;
  for (int i=0;i<chunk;i++) s += cnt[base+i];
  part[t] = s; __syncthreads();
  for (int off=1; off<1024; off<<=1){
    int v = (t>=off) ? part[t-off] : 0;
    __syncthreads();
    part[t] += v;
    __syncthreads();
  }
  int run = (t==0) ? 0 : part[t-1];
  for (int i=0;i<chunk;i++){ rp[base+i] = run; run += cnt[base+i]; }
  if (t == 1023) rp[n] = run;
}

__global__ void k_fill(const int* __restrict__ rows, const int* __restrict__ cols,
                       const float* __restrict__ vals, const int* __restrict__ rp,
                       int* __restrict__ fill, int* __restrict__ bc, float* __restrict__ bv,
                       int E)
{
  int e = blockIdx.x*blockDim.x + threadIdx.x;
  if (e < E){
    int r = rows[e];
    int p = atomicAdd(&fill[r], 1);
    int slot = rp[r] + p;
    bc[slot] = cols[e];
    bv[slot] = vals[e];
  }
}

// ---------------- fused dual SpMM: out[row,:] = sum_s v*Hs[col,:] + sum_f v*Hf[col,:] ----------------
__global__ __launch_bounds__(256) void k_spmm_dual(
    const int* __restrict__ rps, const int* __restrict__ bcs, const float* __restrict__ bvs,
    const unsigned short* __restrict__ Hs,
    const int* __restrict__ rpf, const int* __restrict__ bcf, const float* __restrict__ bvf,
    const unsigned short* __restrict__ Hf,
    unsigned short* __restrict__ out)
{
  int row = blockIdx.x;
  int t = threadIdx.x;
  int c = t << 1;                     // 2 columns per thread
  float a0 = 0.f, a1 = 0.f;
  {
    int j = rps[row], je = rps[row+1];
    for (; j + 4 <= je; j += 4){
      int c0=bcs[j], c1=bcs[j+1], c2=bcs[j+2], c3=bcs[j+3];
      float v0=bvs[j], v1=bvs[j+1], v2=bvs[j+2], v3=bvs[j+3];
      unsigned p0 = *(const unsigned*)(Hs + (size_t)c0*D + c);
      unsigned p1 = *(const unsigned*)(Hs + (size_t)c1*D + c);
      unsigned p2 = *(const unsigned*)(Hs + (size_t)c2*D + c);
      unsigned p3 = *(const unsigned*)(Hs + (size_t)c3*D + c);
      a0 += v0*bf2f(p0&0xffffu) + v1*bf2f(p1&0xffffu) + v2*bf2f(p2&0xffffu) + v3*bf2f(p3&0xffffu);
      a1 += v0*bf2f(p0>>16)     + v1*bf2f(p1>>16)     + v2*bf2f(p2>>16)     + v3*bf2f(p3>>16);
    }
    for (; j < je; j++){
      int cc = bcs[j]; float v = bvs[j];
      unsigned p = *(const unsigned*)(Hs + (size_t)cc*D + c);
      a0 += v*bf2f(p&0xffffu); a1 += v*bf2f(p>>16);
    }
  }
  {
    int j = rpf[row], je = rpf[row+1];
    for (; j + 4 <= je; j += 4){
      int c0=bcf[j], c1=bcf[j+1], c2=bcf[j+2], c3=bcf[j+3];
      float v0=bvf[j], v1=bvf[j+1], v2=bvf[j+2], v3=bvf[j+3];
      unsigned p0 = *(const unsigned*)(Hf + (size_t)c0*D + c);
      unsigned p1 = *(const unsigned*)(Hf + (size_t)c1*D + c);
      unsigned p2 = *(const unsigned*)(Hf + (size_t)c2*D + c);
      unsigned p3 = *(const unsigned*)(Hf + (size_t)c3*D + c);
      a0 += v0*bf2f(p0&0xffffu) + v1*bf2f(p1&0xffffu) + v2*bf2f(p2&0xffffu) + v3*bf2f(p3&0xffffu);
      a1 += v0*bf2f(p0>>16)     + v1*bf2f(p1>>16)     + v2*bf2f(p2>>16)     + v3*bf2f(p3>>16);
    }
    for (; j < je; j++){
      int cc = bcf[j]; float v = bvf[j];
      unsigned p = *(const unsigned*)(Hf + (size_t)cc*D + c);
      a0 += v*bf2f(p&0xffffu); a1 += v*bf2f(p>>16);
    }
  }
  unsigned o = (unsigned)f2bf(a0) | ((unsigned)f2bf(a1) << 16);
  *(unsigned*)(out + (size_t)row*D + c) = o;
}

// ---------------- bf16 MFMA GEMM: C[M,512] = A[M,512] @ B[512,512]^T + bias ----------------
__device__ __forceinline__ void gload16(const unsigned short* g, unsigned short* l){
  __builtin_amdgcn_global_load_lds(
      (const __attribute__((address_space(1))) unsigned int*)(const void*)g,
      (__attribute__((address_space(3))) unsigned int*)(void*)l,
      16, 0, 0);
}

__global__ __launch_bounds__(256) void k_gemm_bias(
    const unsigned short* __restrict__ A,   // [M,512] bf16, row-major (K contiguous)
    const unsigned short* __restrict__ B,   // [512,512] bf16, B[n,k]
    const float* __restrict__ bias,         // [512]
    float* __restrict__ C,                  // [M,512]
    int M)
{
  __shared__ unsigned short Al[128*32];
  __shared__ unsigned short Bl[128*32];
  int bx = blockIdx.x & 3, by = blockIdx.x >> 2;
  int m0 = by << 7, n0 = bx << 7;
  int t = threadIdx.x, wave = t >> 6, lane = t & 63;
  int wr = wave >> 1, wc = wave & 1;        // 2x2 waves, each owns 64x64
  f32x4 acc[4][4] = {};
  int flat = t << 3;                        // bf16 element index in tile, chunk 0
  int r0 = flat >> 5, cc = flat & 31;
  const unsigned short* pa = A + (size_t)(m0 + r0)*D + cc;
  const unsigned short* pb = B + (size_t)(n0 + r0)*D + cc;
  for (int k0 = 0; k0 < D; k0 += 32){
    gload16(pa + k0,                 &Al[flat]);
    gload16(pa + (size_t)64*D + k0,  &Al[flat + 2048]);
    gload16(pb + k0,                 &Bl[flat]);
    gload16(pb + (size_t)64*D + k0,  &Bl[flat + 2048]);
    __syncthreads();
    int arow = (wr << 6) | (lane & 15);
    int brow = (wc << 6) | (lane & 15);
    int kg   = (lane >> 4) << 3;
    bf16x8 af[4], bfr[4];
    #pragma unroll
    for (int mi=0; mi<4; mi++) af[mi]  = *(const bf16x8*)&Al[(arow + (mi<<4))*32 + kg];
    #pragma unroll
    for (int ni=0; ni<4; ni++) bfr[ni] = *(const bf16x8*)&Bl[(brow + (ni<<4))*32 + kg];
    #pragma unroll
    for (int mi=0; mi<4; mi++)
      #pragma unroll
      for (int ni=0; ni<4; ni++)
        acc[mi][ni] = __builtin_amdgcn_mfma_f32_16x16x32_bf16(af[mi], bfr[ni], acc[mi][ni], 0, 0, 0);
    __syncthreads();
  }
  int crow = m0 + (wr << 6) + ((lane >> 4) << 2);
  int ccol = n0 + (wc << 6) + (lane & 15);
  #pragma unroll
  for (int mi=0; mi<4; mi++){
    #pragma unroll
    for (int q=0; q<4; q++){
      int row = crow + (mi << 4) + q;
      float* cp = C + (size_t)row*D + ccol;
      #pragma unroll
      for (int ni=0; ni<4; ni++)
        cp[ni << 4] = acc[mi][ni][q] + bias[ccol + (ni << 4)];
    }
  }
}

// ---------------- LayerNorm + ReLU + subtract hist1[sid1] -> bf16 ----------------
__global__ __launch_bounds__(256) void k_ln_relu_sub(
    const float* __restrict__ y, const float* __restrict__ gam, const float* __restrict__ bet,
    const float* __restrict__ hist1, const int* __restrict__ sid1,
    unsigned short* __restrict__ out)
{
  __shared__ float sh[8];
  int row = blockIdx.x, t = threadIdx.x;
  int c = t << 1;
  float2 v = *(const float2*)(y + (size_t)row*D + c);
  float s = v.x + v.y, ss = v.x*v.x + v.y*v.y;
  #pragma unroll
  for (int m=1; m<64; m<<=1){ s += __shfl_xor(s, m); ss += __shfl_xor(ss, m); }
  int wave = t >> 6, lane = t & 63;
  if (lane == 0){ sh[wave] = s; sh[4+wave] = ss; }
  __syncthreads();
  s  = sh[0]+sh[1]+sh[2]+sh[3];
  ss = sh[4]+sh[5]+sh[6]+sh[7];
  float mu  = s * (1.f/D);
  float var = ss * (1.f/D) - mu*mu;
  float rr  = rsqrtf(var + 1e-5f);
  int srow = sid1[row];
  float2 hv = *(const float2*)(hist1 + (size_t)srow*D + c);
  float o0 = fmaxf((v.x - mu)*rr*gam[c]   + bet[c],   0.f) - hv.x;
  float o1 = fmaxf((v.y - mu)*rr*gam[c+1] + bet[c+1], 0.f) - hv.y;
  *(unsigned*)(out + (size_t)row*D + c) = (unsigned)f2bf(o0) | ((unsigned)f2bf(o1) << 16);
}

// ---------------- log_softmax rows ----------------
__global__ __launch_bounds__(256) void k_logsoftmax(const float* __restrict__ y, float* __restrict__ out){
  __shared__ float sh[8];
  int row = blockIdx.x, t = threadIdx.x;
  int c = t << 1;
  float2 v = *(const float2*)(y + (size_t)row*D + c);
  float m = fmaxf(v.x, v.y);
  #pragma unroll
  for (int k=1; k<64; k<<=1) m = fmaxf(m, __shfl_xor(m, k));
  int wave = t >> 6, lane = t & 63;
  if (lane == 0) sh[wave] = m;
  __syncthreads();
  m = fmaxf(fmaxf(sh[0], sh[1]), fmaxf(sh[2], sh[3]));
  __syncthreads();
  float e = expf(v.x - m) + expf(v.y - m);
  #pragma unroll
  for (int k=1; k<64; k<<=1) e += __shfl_xor(e, k);
  if (lane == 0) sh[4+wave] = e;
  __syncthreads();
  e = sh[4]+sh[5]+sh[6]+sh[7];
  float lse = m + logf(e);
  float2 o; o.x = v.x - lse; o.y = v.y - lse;
  *(float2*)(out + (size_t)row*D + c) = o;
}

extern "C" void kernel_launch(void* const* d_in, const int* in_sizes, int n_in,
                              void* d_out, int out_size, void* d_ws, size_t ws_size,
                              hipStream_t stream)
{
  const float* x     = (const float*)d_in[0];
  const float* hist0 = (const float*)d_in[1];
  const float* hist1 = (const float*)d_in[2];
  const float* w0    = (const float*)d_in[3];
  const float* b0    = (const float*)d_in[4];
  const float* g0    = (const float*)d_in[5];
  const float* beta0 = (const float*)d_in[6];
  const float* w1    = (const float*)d_in[7];
  const float* b1    = (const float*)d_in[8];
  const float* s0v   = (const float*)d_in[9];
  const float* s1v   = (const float*)d_in[10];
  const float* f0v   = (const float*)d_in[11];
  const float* f1v   = (const float*)d_in[12];
  const int* sid0    = (const int*)d_in[13];
  const int* sid1    = (const int*)d_in[14];
  const int* fid0    = (const int*)d_in[16];
  const int* fid1    = (const int*)d_in[17];
  const int* s0r     = (const int*)d_in[18];
  const int* s0c     = (const int*)d_in[19];
  const int* s1r     = (const int*)d_in[20];
  const int* s1c     = (const int*)d_in[21];
  const int* f0r     = (const int*)d_in[22];
  const int* f0c     = (const int*)d_in[23];
  const int* f1r     = (const int*)d_in[24];
  const int* f1c     = (const int*)d_in[25];

  const int N0 = 131072, N1 = 32768, N2 = 8192;
  const int Es0 = 262144, Es1 = 65536, Ef0 = 1048576, Ef1 = 262144;

  char* ws = (char*)d_ws;
  size_t off = 0;
  auto alloc = [&](size_t bytes)->char*{
    char* p = ws + off; off += (bytes + 255) & ~(size_t)255; return p;
  };
  char* regA = alloc((size_t)N0*D*2);    // 128MB: h0 -> later y1 (64MB) + y2 (at +64MB)
  char* regB = alloc((size_t)N0*D*2);    // 128MB: g0buf -> later h1 (at +0) + g1buf (at +64MB)
  char* regC = alloc((size_t)N1*D*2);    // 32MB : out1 -> later out2
  unsigned short* w0b = (unsigned short*)alloc((size_t)D*D*2);
  unsigned short* w1b = (unsigned short*)alloc((size_t)D*D*2);
  int* meta = (int*)alloc((size_t)(N1*4 + N2*4)*4);  // cnt+fill for 4 adjs
  int* cnt_s0 = meta;            int* fill_s0 = cnt_s0 + N1;
  int* cnt_f0 = fill_s0 + N1;    int* fill_f0 = cnt_f0 + N1;
  int* cnt_s1 = fill_f0 + N1;    int* fill_s1 = cnt_s1 + N2;
  int* cnt_f1 = fill_s1 + N2;    int* fill_f1 = cnt_f1 + N2;
  size_t metaBytes = (size_t)(N1*4 + N2*4)*4;
  int* rp_s0 = (int*)alloc((size_t)(N1+1)*4);
  int* rp_f0 = (int*)alloc((size_t)(N1+1)*4);
  int* rp_s1 = (int*)alloc((size_t)(N2+1)*4);
  int* rp_f1 = (int*)alloc((size_t)(N2+1)*4);
  int*   bc_s0 = (int*)alloc((size_t)Es0*4);  float* bv_s0 = (float*)alloc((size_t)Es0*4);
  int*   bc_f0 = (int*)alloc((size_t)Ef0*4);  float* bv_f0 = (float*)alloc((size_t)Ef0*4);
  int*   bc_s1 = (int*)alloc((size_t)Es1*4);  float* bv_s1 = (float*)alloc((size_t)Es1*4);
  int*   bc_f1 = (int*)alloc((size_t)Ef1*4);  float* bv_f1 = (float*)alloc((size_t)Ef1*4);

  unsigned short* h0    = (unsigned short*)regA;
  unsigned short* g0buf = (unsigned short*)regB;
  unsigned short* out1  = (unsigned short*)regC;
  float*          y1    = (float*)regA;                              // after spmm0 (h0 dead)
  unsigned short* h1    = (unsigned short*)regB;                     // after spmm0 (g0 dead)
  unsigned short* g1buf = (unsigned short*)(regB + ((size_t)64<<20));
  unsigned short* out2  = (unsigned short*)regC;                     // after gemm0 (out1 dead)
  float*          y2    = (float*)(regA + ((size_t)64<<20));
  float*          outp  = (float*)d_out;

  hipMemsetAsync(meta, 0, metaBytes, stream);
  k_f2b<<<(D*D + 255)/256, 256, 0, stream>>>(w0, w0b, D*D);
  k_f2b<<<(D*D + 255)/256, 256, 0, stream>>>(w1, w1b, D*D);
  k_gather_sub_bf16<<<N0*128/256, 256, 0, stream>>>(x, hist0, sid0, h0, N0);
  k_gather_sub_bf16<<<N0*128/256, 256, 0, stream>>>(hist0, nullptr, fid0, g0buf, N0);
  k_count<<<Es0/256, 256, 0, stream>>>(s0r, cnt_s0, Es0);
  k_count<<<Ef0/256, 256, 0, stream>>>(f0r, cnt_f0, Ef0);
  k_count<<<Es1/256, 256, 0, stream>>>(s1r, cnt_s1, Es1);
  k_count<<<Ef1/256, 256, 0, stream>>>(f1r, cnt_f1, Ef1);
  k_exscan4<<<4, 1024, 0, stream>>>(cnt_s0, rp_s0, N1, cnt_f0, rp_f0, N1,
                                    cnt_s1, rp_s1, N2, cnt_f1, rp_f1, N2);
  k_fill<<<Es0/256, 256, 0, stream>>>(s0r, s0c, s0v, rp_s0, fill_s0, bc_s0, bv_s0, Es0);
  k_fill<<<Ef0/256, 256, 0, stream>>>(f0r, f0c, f0v, rp_f0, fill_f0, bc_f0, bv_f0, Ef0);
  k_fill<<<Es1/256, 256, 0, stream>>>(s1r, s1c, s1v, rp_s1, fill_s1, bc_s1, bv_s1, Es1);
  k_fill<<<Ef1/256, 256, 0, stream>>>(f1r, f1c, f1v, rp_f1, fill_f1, bc_f1, bv_f1, Ef1);
  // layer 0
  k_spmm_dual<<<N1, 256, 0, stream>>>(rp_s0, bc_s0, bv_s0, h0, rp_f0, bc_f0, bv_f0, g0buf, out1);
  k_gather_sub_bf16<<<N1*128/256, 256, 0, stream>>>(hist1, nullptr, fid1, g1buf, N1);
  k_gemm_bias<<<(N1/128)*4, 256, 0, stream>>>(out1, w0b, b0, y1, N1);
  k_ln_relu_sub<<<N1, 256, 0, stream>>>(y1, g0, beta0, hist1, sid1, h1);
  // layer 1
  k_spmm_dual<<<N2, 256, 0, stream>>>(rp_s1, bc_s1, bv_s1, h1, rp_f1, bc_f1, bv_f1, g1buf, out2);
  k_gemm_bias<<<(N2/128)*4, 256, 0, stream>>>(out2, w1b, b1, y2, N2);
  k_logsoftmax<<<N2, 256, 0, stream>>>(y2, outp);
}